// Round 1
// baseline (226.503 us; speedup 1.0000x reference)
//
#include <hip/hip_runtime.h>
#include <hip/hip_bf16.h>

// MDTA: LN -> 1x1 conv (QKV) -> dw3x3 -> spatial attention (N=4096, d=24, 8 heads) -> proj + residual
// Strategy: bf16 MFMA for the three matmul stages, flash-style attention (never materialize S: 537MB).

typedef __bf16 bf16;
typedef __bf16 bf16x8 __attribute__((ext_vector_type(8)));
typedef float f32x4 __attribute__((ext_vector_type(4)));

#define C_DIM 192
#define N_PIX 4096
#define HEADS 8
#define DHEAD 24
#define DPAD 32
#define C3 576

__device__ inline float fast_exp2(float x) {
#if __has_builtin(__builtin_amdgcn_exp2f)
    return __builtin_amdgcn_exp2f(x);
#else
    return exp2f(x);
#endif
}

__device__ inline f32x4 mfma16(bf16x8 a, bf16x8 b, f32x4 c) {
    return __builtin_amdgcn_mfma_f32_16x16x32_bf16(a, b, c, 0, 0, 0);
}

// ---------------- prep: fp32 weights -> bf16 ----------------
__global__ __launch_bounds__(256) void prep_weights(const float* __restrict__ wqkv,
                                                    const float* __restrict__ wproj,
                                                    bf16* __restrict__ wqkv_b,
                                                    bf16* __restrict__ wproj_b) {
    int i = blockIdx.x * 256 + threadIdx.x;
    if (i < C3 * C_DIM) wqkv_b[i] = (bf16)wqkv[i];
    if (i < C_DIM * C_DIM) wproj_b[i] = (bf16)wproj[i];
}

// ---------------- LayerNorm over C per pixel; write x_ln transposed (p, c) bf16 ----------------
__global__ __launch_bounds__(256) void ln_kernel(const float* __restrict__ x,
                                                 const float* __restrict__ gamma,
                                                 const float* __restrict__ beta,
                                                 bf16* __restrict__ xln_t) {
    int p = blockIdx.x * 256 + threadIdx.x;
    float s = 0.f, ss = 0.f;
    for (int c = 0; c < C_DIM; ++c) {
        float v = x[c * N_PIX + p];
        s += v; ss += v * v;
    }
    float mean = s * (1.0f / C_DIM);
    float var = ss * (1.0f / C_DIM) - mean * mean;
    float rstd = rsqrtf(var + 1e-5f);
    for (int c = 0; c < C_DIM; c += 8) {
        bf16x8 v8;
        for (int j = 0; j < 8; ++j) {
            float v = (x[(c + j) * N_PIX + p] - mean) * rstd * gamma[c + j] + beta[c + j];
            v8[j] = (bf16)v;
        }
        *(bf16x8*)(xln_t + p * C_DIM + c) = v8;
    }
}

// ---------------- GEMM: out[M,4096] = A[M,192] * BT[4096,192]^T ; K=192 ----------------
// outb!=null: bf16 out. outf!=null: fp32 out + resid (residual add).
__global__ __launch_bounds__(256) void gemm192(const bf16* __restrict__ A,
                                               const bf16* __restrict__ BT,
                                               bf16* __restrict__ outb,
                                               float* __restrict__ outf,
                                               const float* __restrict__ resid) {
    const int K = 192;
    int n0 = blockIdx.x * 64;
    int m0 = blockIdx.y * 64;
    int tid = threadIdx.x;
    int wave = tid >> 6, lane = tid & 63;
    int l16 = lane & 15, quad = lane >> 4;
    int wm = (wave >> 1) * 32, wn = (wave & 1) * 32;
    f32x4 acc[2][2] = {};
    for (int kk = 0; kk < K; kk += 32) {
        bf16x8 a0 = *(const bf16x8*)(A + (m0 + wm + l16) * K + kk + quad * 8);
        bf16x8 a1 = *(const bf16x8*)(A + (m0 + wm + 16 + l16) * K + kk + quad * 8);
        bf16x8 b0 = *(const bf16x8*)(BT + (n0 + wn + l16) * K + kk + quad * 8);
        bf16x8 b1 = *(const bf16x8*)(BT + (n0 + wn + 16 + l16) * K + kk + quad * 8);
        acc[0][0] = mfma16(a0, b0, acc[0][0]);
        acc[0][1] = mfma16(a0, b1, acc[0][1]);
        acc[1][0] = mfma16(a1, b0, acc[1][0]);
        acc[1][1] = mfma16(a1, b1, acc[1][1]);
    }
    for (int i = 0; i < 2; ++i)
        for (int j = 0; j < 2; ++j)
            for (int r = 0; r < 4; ++r) {
                int row = m0 + wm + i * 16 + quad * 4 + r;  // C/D: row=(lane>>4)*4+reg
                int col = n0 + wn + j * 16 + l16;           // C/D: col=lane&15
                float v = acc[i][j][r];
                if (outf) outf[row * N_PIX + col] = v + resid[row * N_PIX + col];
                else outb[row * N_PIX + col] = (bf16)v;
            }
}

// ---------------- depthwise 3x3 + bias; scatter into attention layouts ----------------
// q: qt[h][n][dd] (dd pad to 32, zeros), k: kt same, v: vl[h][dd][n] (dd pad to 32, zeros)
__global__ __launch_bounds__(256) void dwconv(const bf16* __restrict__ qkv,
                                              const float* __restrict__ wdw,
                                              const float* __restrict__ bdw,
                                              bf16* __restrict__ qt,
                                              bf16* __restrict__ kt,
                                              bf16* __restrict__ vl) {
    int ch = blockIdx.x >> 4;
    int p = (blockIdx.x & 15) * 256 + threadIdx.x;
    if (ch >= C3) {
        // zero the d-pad rows (they participate in MFMA contraction / get read as B cols)
        int i = ch - C3;          // 0..191
        int part = i >> 6;        // 0=q,1=k,2=v
        int rem = i & 63;
        int h = rem >> 3, dd = 24 + (rem & 7);
        bf16 z = (bf16)0.0f;
        if (part == 0) qt[(h * N_PIX + p) * DPAD + dd] = z;
        else if (part == 1) kt[(h * N_PIX + p) * DPAD + dd] = z;
        else vl[(h * DPAD + dd) * N_PIX + p] = z;
        return;
    }
    int y = p >> 6, xx = p & 63;
    const bf16* in = qkv + ch * N_PIX;
    float w[9];
    for (int t = 0; t < 9; ++t) w[t] = wdw[ch * 9 + t];
    float acc = bdw[ch];
    for (int dy = -1; dy <= 1; ++dy) {
        int yy = y + dy;
        if (yy < 0 || yy > 63) continue;
        for (int dx = -1; dx <= 1; ++dx) {
            int xc = xx + dx;
            if (xc < 0 || xc > 63) continue;
            acc += w[(dy + 1) * 3 + (dx + 1)] * (float)in[yy * 64 + xc];
        }
    }
    int part = ch / C_DIM, c = ch % C_DIM;
    int h = c / DHEAD, dd = c % DHEAD;
    bf16 v = (bf16)acc;
    if (part == 0) qt[(h * N_PIX + p) * DPAD + dd] = v;
    else if (part == 1) kt[(h * N_PIX + p) * DPAD + dd] = v;
    else vl[(h * DPAD + dd) * N_PIX + p] = v;
}

// ---------------- flash attention ----------------
// Block = 1 head x 64 queries (4 waves, 16 rows each). Iterate keys in chunks of 64.
// S tile via mfma(Aq, Bk): D[row=n][col=m]. Online softmax in base-2 domain.
// P -> LDS (C/D layout -> A-operand layout), PV via mfma(Ap, Bv): D[row=n][col=dd].
__global__ __launch_bounds__(256) void flash_attn(const bf16* __restrict__ qt,
                                                  const bf16* __restrict__ kt,
                                                  const bf16* __restrict__ vl,
                                                  const float* __restrict__ temp,
                                                  bf16* __restrict__ outt) {
    __shared__ __align__(16) bf16 Klds[64 * 32];       // [m_local][dd] stride 32 (64B: 2-way, free)
    __shared__ __align__(16) bf16 Vlds[32 * 72];       // [dd][m_local] stride 72 (pad kills 16-way conflict)
    __shared__ __align__(16) bf16 Plds[4 * 16 * 72];   // per-wave [n_local][m_local] stride 72

    int tid = threadIdx.x;
    int wave = tid >> 6, lane = tid & 63;
    int l16 = lane & 15, quad = lane >> 4;
    int head = blockIdx.x & 7;          // head = bx&7 -> same-head blocks share an XCD L2
    int n0 = (blockIdx.x >> 3) * 64;
    int nbase = n0 + wave * 16;
    float tscale = temp[head] * 1.44269504f;  // fold log2(e): softmax in exp2 domain

    // Q fragment (A-operand): A[n=lane&15][k=quad*8+j], held all kernel
    bf16x8 aq = *(const bf16x8*)(qt + ((head * N_PIX) + nbase + l16) * DPAD + quad * 8);

    f32x4 o0 = {0.f, 0.f, 0.f, 0.f}, o1 = {0.f, 0.f, 0.f, 0.f};
    float run_m[4], run_l[4];
    for (int r = 0; r < 4; ++r) { run_m[r] = -3.0e38f; run_l[r] = 0.f; }

    int krow = tid >> 2, kcol = (tid & 3) * 8;   // 64 rows x 32
    int vrow = tid >> 3, vcol = (tid & 7) * 8;   // 32 rows x 64
    bf16* pbase = Plds + wave * (16 * 72);

    for (int m0 = 0; m0 < N_PIX; m0 += 64) {
        __syncthreads();
        *(bf16x8*)(Klds + krow * 32 + kcol) =
            *(const bf16x8*)(kt + ((head * N_PIX) + m0 + krow) * DPAD + kcol);
        *(bf16x8*)(Vlds + vrow * 72 + vcol) =
            *(const bf16x8*)(vl + (head * DPAD + vrow) * N_PIX + m0 + vcol);
        __syncthreads();

        // S = Q^T K for 4 m-tiles of 16
        f32x4 s[4];
        for (int mt = 0; mt < 4; ++mt) {
            bf16x8 bk = *(const bf16x8*)(Klds + (mt * 16 + l16) * 32 + quad * 8);
            f32x4 z = {0.f, 0.f, 0.f, 0.f};
            s[mt] = mfma16(aq, bk, z);
        }
        for (int mt = 0; mt < 4; ++mt)
            for (int r = 0; r < 4; ++r) s[mt][r] *= tscale;

        // online softmax stats; row r lives in 16 lanes sharing (lane>>4)
        float newm[4], alpha[4];
        for (int r = 0; r < 4; ++r) {
            float mx = fmaxf(fmaxf(s[0][r], s[1][r]), fmaxf(s[2][r], s[3][r]));
            for (int off = 1; off < 16; off <<= 1)
                mx = fmaxf(mx, __shfl_xor(mx, off, 64));
            float nm = fmaxf(run_m[r], mx);
            alpha[r] = fast_exp2(run_m[r] - nm);
            newm[r] = nm;
        }
        float rs[4] = {0.f, 0.f, 0.f, 0.f};
        for (int mt = 0; mt < 4; ++mt)
            for (int r = 0; r < 4; ++r) {
                float pv = fast_exp2(s[mt][r] - newm[r]);
                rs[r] += pv;
                pbase[(quad * 4 + r) * 72 + mt * 16 + l16] = (bf16)pv;
            }
        for (int r = 0; r < 4; ++r) {
            float t = rs[r];
            for (int off = 1; off < 16; off <<= 1) t += __shfl_xor(t, off, 64);
            run_l[r] = run_l[r] * alpha[r] + t;
            run_m[r] = newm[r];
            o0[r] *= alpha[r];
            o1[r] *= alpha[r];
        }

        // O += P * V^T : A[n][k=m] from Plds, B cols = dd from Vlds
        for (int kc = 0; kc < 2; ++kc) {
            bf16x8 ap = *(const bf16x8*)(pbase + l16 * 72 + kc * 32 + quad * 8);
            bf16x8 bv0 = *(const bf16x8*)(Vlds + l16 * 72 + kc * 32 + quad * 8);
            bf16x8 bv1 = *(const bf16x8*)(Vlds + (16 + l16) * 72 + kc * 32 + quad * 8);
            o0 = mfma16(ap, bv0, o0);
            o1 = mfma16(ap, bv1, o1);
        }
    }

    // epilogue: O/l -> outt[n][c] (proj's BT layout), c = head*24 + dd (dd<24 only)
    for (int r = 0; r < 4; ++r) {
        float inv = 1.0f / run_l[r];
        int n = nbase + quad * 4 + r;
        outt[n * C_DIM + head * DHEAD + l16] = (bf16)(o0[r] * inv);
        if (l16 < 8)
            outt[n * C_DIM + head * DHEAD + 16 + l16] = (bf16)(o1[r] * inv);
    }
}

extern "C" void kernel_launch(void* const* d_in, const int* in_sizes, int n_in,
                              void* d_out, int out_size, void* d_ws, size_t ws_size,
                              hipStream_t stream) {
    const float* x     = (const float*)d_in[0];
    const float* gamma = (const float*)d_in[1];
    const float* beta  = (const float*)d_in[2];
    const float* wqkv  = (const float*)d_in[3];
    const float* wdw   = (const float*)d_in[4];
    const float* bdw   = (const float*)d_in[5];
    const float* wproj = (const float*)d_in[6];
    const float* temp  = (const float*)d_in[7];
    float* out = (float*)d_out;

    // workspace layout (bytes), total ~14.5 MB
    char* ws = (char*)d_ws;
    bf16* wqkv_b = (bf16*)(ws + 0);          // 576*192*2   = 221184
    bf16* wproj_b = (bf16*)(ws + 221184);    // 192*192*2   = 73728
    bf16* xln    = (bf16*)(ws + 294912);     // 4096*192*2  = 1572864
    bf16* qkv    = (bf16*)(ws + 1867776);    // 576*4096*2  = 4718592
    bf16* qt     = (bf16*)(ws + 6586368);    // 8*4096*32*2 = 2097152
    bf16* kt     = (bf16*)(ws + 8683520);    // 2097152
    bf16* vl     = (bf16*)(ws + 10780672);   // 8*32*4096*2 = 2097152
    bf16* outt   = (bf16*)(ws + 12877824);   // 4096*192*2  = 1572864

    prep_weights<<<576, 256, 0, stream>>>(wqkv, wproj, wqkv_b, wproj_b);
    ln_kernel<<<16, 256, 0, stream>>>(x, gamma, beta, xln);
    gemm192<<<dim3(64, 9), 256, 0, stream>>>(wqkv_b, xln, qkv, nullptr, nullptr);
    dwconv<<<(C3 + 192) * 16, 256, 0, stream>>>(qkv, wdw, bdw, qt, kt, vl);
    flash_attn<<<512, 256, 0, stream>>>(qt, kt, vl, temp, outt);
    gemm192<<<dim3(64, 3), 256, 0, stream>>>(wproj_b, outt, nullptr, out, x);
}

// Round 2
// 177.846 us; speedup vs baseline: 1.2736x; 1.2736x over previous
//
#include <hip/hip_runtime.h>
#include <hip/hip_bf16.h>

// MDTA: LN -> 1x1 conv (QKV) -> dw3x3 -> spatial attention (N=4096, d=24, 8 heads) -> proj + residual
// Flash attention with FIXED-BOUND softmax (no per-iter cross-lane reductions),
// double-buffered LDS staging, split-K=3 for occupancy.

typedef __bf16 bf16;
typedef __bf16 bf16x8 __attribute__((ext_vector_type(8)));
typedef float f32x4 __attribute__((ext_vector_type(4)));

#define C_DIM 192
#define N_PIX 4096
#define HEADS 8
#define DHEAD 24
#define DPAD 32
#define C3 576
#define NSPLIT 3

__device__ inline float fast_exp2(float x) {
#if __has_builtin(__builtin_amdgcn_exp2f)
    return __builtin_amdgcn_exp2f(x);
#else
    return exp2f(x);
#endif
}

__device__ inline f32x4 mfma16(bf16x8 a, bf16x8 b, f32x4 c) {
    return __builtin_amdgcn_mfma_f32_16x16x32_bf16(a, b, c, 0, 0, 0);
}

// ---------------- prep: fp32 weights -> bf16 ----------------
__global__ __launch_bounds__(256) void prep_weights(const float* __restrict__ wqkv,
                                                    const float* __restrict__ wproj,
                                                    bf16* __restrict__ wqkv_b,
                                                    bf16* __restrict__ wproj_b) {
    int i = blockIdx.x * 256 + threadIdx.x;
    if (i < C3 * C_DIM) wqkv_b[i] = (bf16)wqkv[i];
    if (i < C_DIM * C_DIM) wproj_b[i] = (bf16)wproj[i];
}

// ---------------- LayerNorm over C per pixel; write x_ln transposed (p, c) bf16 ----------------
// block = 64 pixels x 4 channel-quarters (one wave each); x cached in registers.
__global__ __launch_bounds__(256) void ln_kernel(const float* __restrict__ x,
                                                 const float* __restrict__ gamma,
                                                 const float* __restrict__ beta,
                                                 bf16* __restrict__ xln_t) {
    __shared__ float sred[4][64], ssred[4][64];
    int tid = threadIdx.x;
    int pl = tid & 63, cq = tid >> 6;
    int p = blockIdx.x * 64 + pl;
    float vals[48];
    float s = 0.f, ss = 0.f;
    for (int j = 0; j < 48; ++j) {
        float v = x[(cq * 48 + j) * N_PIX + p];
        vals[j] = v; s += v; ss += v * v;
    }
    sred[cq][pl] = s; ssred[cq][pl] = ss;
    __syncthreads();
    float S = sred[0][pl] + sred[1][pl] + sred[2][pl] + sred[3][pl];
    float SS = ssred[0][pl] + ssred[1][pl] + ssred[2][pl] + ssred[3][pl];
    float mean = S * (1.0f / C_DIM);
    float var = SS * (1.0f / C_DIM) - mean * mean;
    float rstd = rsqrtf(var + 1e-5f);
    for (int g = 0; g < 6; ++g) {
        bf16x8 v8;
        for (int j = 0; j < 8; ++j) {
            int c = cq * 48 + g * 8 + j;
            v8[j] = (bf16)((vals[g * 8 + j] - mean) * rstd * gamma[c] + beta[c]);
        }
        *(bf16x8*)(xln_t + p * C_DIM + cq * 48 + g * 8) = v8;
    }
}

// ---------------- GEMM: out[M,4096] = A[M,192] * BT[4096,192]^T ; K=192 ----------------
__global__ __launch_bounds__(256) void gemm192(const bf16* __restrict__ A,
                                               const bf16* __restrict__ BT,
                                               bf16* __restrict__ outb,
                                               float* __restrict__ outf,
                                               const float* __restrict__ resid) {
    const int K = 192;
    int n0 = blockIdx.x * 64;
    int m0 = blockIdx.y * 64;
    int tid = threadIdx.x;
    int wave = tid >> 6, lane = tid & 63;
    int l16 = lane & 15, quad = lane >> 4;
    int wm = (wave >> 1) * 32, wn = (wave & 1) * 32;
    f32x4 acc[2][2] = {};
    for (int kk = 0; kk < K; kk += 32) {
        bf16x8 a0 = *(const bf16x8*)(A + (m0 + wm + l16) * K + kk + quad * 8);
        bf16x8 a1 = *(const bf16x8*)(A + (m0 + wm + 16 + l16) * K + kk + quad * 8);
        bf16x8 b0 = *(const bf16x8*)(BT + (n0 + wn + l16) * K + kk + quad * 8);
        bf16x8 b1 = *(const bf16x8*)(BT + (n0 + wn + 16 + l16) * K + kk + quad * 8);
        acc[0][0] = mfma16(a0, b0, acc[0][0]);
        acc[0][1] = mfma16(a0, b1, acc[0][1]);
        acc[1][0] = mfma16(a1, b0, acc[1][0]);
        acc[1][1] = mfma16(a1, b1, acc[1][1]);
    }
    for (int i = 0; i < 2; ++i)
        for (int j = 0; j < 2; ++j)
            for (int r = 0; r < 4; ++r) {
                int row = m0 + wm + i * 16 + quad * 4 + r;
                int col = n0 + wn + j * 16 + l16;
                float v = acc[i][j][r];
                if (outf) outf[row * N_PIX + col] = v + resid[row * N_PIX + col];
                else outb[row * N_PIX + col] = (bf16)v;
            }
}

// ---------------- depthwise 3x3 + bias; coalesced scatter into attention layouts ----------------
// block = (part,h) x 256-pixel tile. Thread computes all 24 channels of its pixel.
// part 1 (k) additionally feeds max||k||^2 via atomicMax (monotone uint trick).
__global__ __launch_bounds__(256) void dwconv(const bf16* __restrict__ qkv,
                                              const float* __restrict__ wdw,
                                              const float* __restrict__ bdw,
                                              bf16* __restrict__ qt,
                                              bf16* __restrict__ kt,
                                              bf16* __restrict__ vl,
                                              float* __restrict__ maxk2) {
    int bh = blockIdx.x >> 4;          // 0..23 = part*8 + h
    int tile = blockIdx.x & 15;
    int part = bh >> 3, h = bh & 7;
    int p = tile * 256 + threadIdx.x;
    int y = p >> 6, xx = p & 63;
    int ch0 = part * C_DIM + h * DHEAD;

    float acc[24];
    for (int j = 0; j < 24; ++j) acc[j] = bdw[ch0 + j];
    for (int j = 0; j < 24; ++j) {
        const bf16* in = qkv + (ch0 + j) * N_PIX;
        const float* w = wdw + (ch0 + j) * 9;
        float a = 0.f;
        for (int dy = -1; dy <= 1; ++dy) {
            int yy = y + dy;
            if (yy < 0 || yy > 63) continue;
            for (int dx = -1; dx <= 1; ++dx) {
                int xc = xx + dx;
                if (xc < 0 || xc > 63) continue;
                a += w[(dy + 1) * 3 + (dx + 1)] * (float)in[yy * 64 + xc];
            }
        }
        acc[j] += a;
    }

    if (part < 2) {
        bf16* dst = (part == 0 ? qt : kt) + (h * N_PIX + p) * DPAD;
        for (int g = 0; g < 3; ++g) {
            bf16x8 v8;
            for (int j = 0; j < 8; ++j) v8[j] = (bf16)acc[g * 8 + j];
            *(bf16x8*)(dst + g * 8) = v8;
        }
        bf16x8 z;
        for (int j = 0; j < 8; ++j) z[j] = (bf16)0.0f;
        *(bf16x8*)(dst + 24) = z;
        if (part == 1) {
            float s2 = 0.f;
            for (int j = 0; j < 24; ++j) s2 += acc[j] * acc[j];
            for (int off = 1; off < 64; off <<= 1)
                s2 = fmaxf(s2, __shfl_xor(s2, off, 64));
            if ((threadIdx.x & 63) == 0)
                atomicMax((unsigned int*)(maxk2 + h), __float_as_uint(s2));
        }
    } else {
        for (int j = 0; j < 24; ++j) vl[(h * DPAD + j) * N_PIX + p] = (bf16)acc[j];
        for (int j = 24; j < 32; ++j) vl[(h * DPAD + j) * N_PIX + p] = (bf16)0.0f;
    }
}

// ---------------- flash attention, fixed-bound softmax, split-K ----------------
__global__ __launch_bounds__(256, 6) void flash_attn(const bf16* __restrict__ qt,
                                                     const bf16* __restrict__ kt,
                                                     const bf16* __restrict__ vl,
                                                     const float* __restrict__ temp,
                                                     const float* __restrict__ maxk2,
                                                     bf16* __restrict__ opart,
                                                     float* __restrict__ lpart) {
    __shared__ __align__(16) bf16 Klds[2][64 * 32];
    __shared__ __align__(16) bf16 Vlds[2][32 * 72];
    __shared__ __align__(16) bf16 Plds[4 * 16 * 72];

    int tid = threadIdx.x;
    int wave = tid >> 6, lane = tid & 63;
    int l16 = lane & 15, quad = lane >> 4;
    int head = blockIdx.x & 7;
    int qb = (blockIdx.x >> 3) & 63;
    int split = blockIdx.x >> 9;           // 0..2
    int n0 = qb * 64, nbase = n0 + wave * 16;
    int t0 = (split * 64) / NSPLIT, t1 = ((split + 1) * 64) / NSPLIT;
    int NITER = t1 - t0;
    int mstart = t0 * 64;
    float tl = temp[head] * 1.44269504f;

    // Q fragment (A-operand): A[n=lane&15][k=quad*8+j]
    bf16x8 aq = *(const bf16x8*)(qt + ((head * N_PIX) + nbase + l16) * DPAD + quad * 8);

    // per-row upper bound B[r] = |t*log2e| * ||q_row|| * max||k|| + 1
    float q2 = 0.f;
    for (int j = 0; j < 8; ++j) { float f = (float)aq[j]; q2 += f * f; }
    q2 += __shfl_xor(q2, 16, 64);
    q2 += __shfl_xor(q2, 32, 64);
    float mk2 = maxk2[head];
    float B[4];
    for (int r = 0; r < 4; ++r) {
        float q2r = __shfl(q2, quad * 4 + r, 64);
        B[r] = fabsf(tl) * sqrtf(q2r * mk2) + 1.0f;
    }

    int krow = tid >> 2, kcol = (tid & 3) * 8;   // 64 rows x 32
    int vrow = tid >> 3, vcol = (tid & 7) * 8;   // 32 rows x 64
    bf16* pbase = Plds + wave * (16 * 72);

    // stage tile 0 into buf 0
    *(bf16x8*)(&Klds[0][krow * 32 + kcol]) =
        *(const bf16x8*)(kt + ((head * N_PIX) + mstart + krow) * DPAD + kcol);
    *(bf16x8*)(&Vlds[0][vrow * 72 + vcol]) =
        *(const bf16x8*)(vl + (head * DPAD + vrow) * N_PIX + mstart + vcol);

    f32x4 o0 = {0.f, 0.f, 0.f, 0.f}, o1 = {0.f, 0.f, 0.f, 0.f};
    float rs[4] = {0.f, 0.f, 0.f, 0.f};

    for (int it = 0; it < NITER; ++it) {
        int p = it & 1;
        __syncthreads();   // tile `it` visible in buf p
        bool pre = (it + 1 < NITER);
        bf16x8 kreg, vreg;
        if (pre) {
            int m1 = mstart + (it + 1) * 64;
            kreg = *(const bf16x8*)(kt + ((head * N_PIX) + m1 + krow) * DPAD + kcol);
            vreg = *(const bf16x8*)(vl + (head * DPAD + vrow) * N_PIX + m1 + vcol);
        }
        // S = Q K^T (rows n, cols m)
        f32x4 s[4];
        for (int mt = 0; mt < 4; ++mt) {
            bf16x8 bk = *(const bf16x8*)(&Klds[p][(mt * 16 + l16) * 32 + quad * 8]);
            f32x4 z = {0.f, 0.f, 0.f, 0.f};
            s[mt] = mfma16(aq, bk, z);
        }
        // P = exp2(s*tl - B); per-lane partial row sums (reduced once at the end)
        for (int mt = 0; mt < 4; ++mt) {
            for (int r = 0; r < 4; ++r) {
                float pv = fast_exp2(__builtin_fmaf(s[mt][r], tl, -B[r]));
                rs[r] += pv;
                pbase[(quad * 4 + r) * 72 + mt * 16 + l16] = (bf16)pv;
            }
        }
        // O += P V^T
        for (int kc = 0; kc < 2; ++kc) {
            bf16x8 ap = *(const bf16x8*)(pbase + l16 * 72 + kc * 32 + quad * 8);
            bf16x8 bv0 = *(const bf16x8*)(&Vlds[p][l16 * 72 + kc * 32 + quad * 8]);
            bf16x8 bv1 = *(const bf16x8*)(&Vlds[p][(16 + l16) * 72 + kc * 32 + quad * 8]);
            o0 = mfma16(ap, bv0, o0);
            o1 = mfma16(ap, bv1, o1);
        }
        // stage tile it+1 into the other buffer (reads of it-1 from it finished at top barrier)
        if (pre) {
            *(bf16x8*)(&Klds[1 - p][krow * 32 + kcol]) = kreg;
            *(bf16x8*)(&Vlds[1 - p][vrow * 72 + vcol]) = vreg;
        }
    }

    // one-time row-sum reduction across the 16 column-lanes
    for (int r = 0; r < 4; ++r) {
        float t = rs[r];
        for (int off = 1; off < 16; off <<= 1) t += __shfl_xor(t, off, 64);
        rs[r] = t;
    }
    // store unnormalized partials (bf16 O, fp32 l)
    for (int r = 0; r < 4; ++r) {
        int n = nbase + quad * 4 + r;
        bf16* orow = opart + ((size_t)(split * 8 + head) * N_PIX + n) * 24;
        orow[l16] = (bf16)o0[r];
        if (l16 < 8) orow[16 + l16] = (bf16)o1[r];
        if (l16 == 0) lpart[(size_t)(split * 8 + head) * N_PIX + n] = rs[r];
    }
}

// ---------------- combine split-K partials -> outt[n][c] bf16 ----------------
__global__ __launch_bounds__(256) void combine(const bf16* __restrict__ opart,
                                               const float* __restrict__ lpart,
                                               bf16* __restrict__ outt) {
    int idx = blockIdx.x * 256 + threadIdx.x;   // 8*4096*24 exactly
    int dd = idx % 24;
    int rest = idx / 24;
    int n = rest & 4095;
    int h = rest >> 12;
    float o = 0.f, l = 0.f;
    for (int s = 0; s < NSPLIT; ++s) {
        o += (float)opart[((size_t)(s * 8 + h) * N_PIX + n) * 24 + dd];
        l += lpart[(size_t)(s * 8 + h) * N_PIX + n];
    }
    outt[n * C_DIM + h * DHEAD + dd] = (bf16)(o / l);
}

extern "C" void kernel_launch(void* const* d_in, const int* in_sizes, int n_in,
                              void* d_out, int out_size, void* d_ws, size_t ws_size,
                              hipStream_t stream) {
    const float* x     = (const float*)d_in[0];
    const float* gamma = (const float*)d_in[1];
    const float* beta  = (const float*)d_in[2];
    const float* wqkv  = (const float*)d_in[3];
    const float* wdw   = (const float*)d_in[4];
    const float* bdw   = (const float*)d_in[5];
    const float* wproj = (const float*)d_in[6];
    const float* temp  = (const float*)d_in[7];
    float* out = (float*)d_out;

    // workspace layout (bytes) ~14.85 MB; opart aliases xln+qkv (dead before flash)
    char* ws = (char*)d_ws;
    bf16* wqkv_b  = (bf16*)(ws + 0);          // 221184
    bf16* wproj_b = (bf16*)(ws + 221184);     // 73728
    bf16* xln     = (bf16*)(ws + 294912);     // 1572864
    bf16* qkv     = (bf16*)(ws + 1867776);    // 4718592
    bf16* opart   = (bf16*)(ws + 294912);     // 3*8*4096*24*2 = 4718592 (alias xln+qkv)
    bf16* qt      = (bf16*)(ws + 6586368);    // 2097152
    bf16* kt      = (bf16*)(ws + 8683520);    // 2097152
    bf16* vl      = (bf16*)(ws + 10780672);   // 2097152
    bf16* outt    = (bf16*)(ws + 12877824);   // 1572864
    float* lpart  = (float*)(ws + 14450688);  // 3*8*4096*4 = 393216
    float* maxk2  = (float*)(ws + 14843904);  // 32

    prep_weights<<<576, 256, 0, stream>>>(wqkv, wproj, wqkv_b, wproj_b);
    ln_kernel<<<64, 256, 0, stream>>>(x, gamma, beta, xln);
    gemm192<<<dim3(64, 9), 256, 0, stream>>>(wqkv_b, xln, qkv, nullptr, nullptr);
    hipMemsetAsync(maxk2, 0, 32, stream);
    dwconv<<<24 * 16, 256, 0, stream>>>(qkv, wdw, bdw, qt, kt, vl, maxk2);
    flash_attn<<<NSPLIT * 512, 256, 0, stream>>>(qt, kt, vl, temp, maxk2, opart, lpart);
    combine<<<3072, 256, 0, stream>>>(opart, lpart, outt);
    gemm192<<<dim3(64, 3), 256, 0, stream>>>(wproj_b, outt, nullptr, out, x);
}